// Round 12
// baseline (138.470 us; speedup 1.0000x reference)
//
#include <hip/hip_runtime.h>
#include <hip/hip_bf16.h>

// Windowed attention smoothing via MFMA — barrier-free, per-wave autonomous.
// v10 = v5 (proven 42.4us) + IN-REGISTER SOFTMAX (Sc LDS round-trip deleted):
//   - After M2, lane (m16,quad) holds S[i][m16] for i=it*16+quad*4+rg.
//     Window membership (i-m16 in [0,10]) is a per-lane-constant test;
//     masked scores -> -3e38 (exp -> exactly 0). Max/sum reduced across
//     the 4 quads of a column via __shfl_xor(16/32) butterflies.
//     Identical math: same max set, same __expf(x*0.125), fp32 normalize.
//   - P4 readlane sources sm[i>>4][i&3] from lane ((i&15)>>2)*16+rr
//     (compile-time) — same 176 readlane+fma as v5.
//   - LDS 39680 -> 31552 B/block => 5 blocks/CU (20 waves, +25% TLP);
//     grid 1280. Removes 8 ds_write + 11 serial ds_read from the chain.
// exp2/rcp builtins REVERTED PERMANENTLY: v8/v9 bisect showed they alone
// cause +16MiB scratch writes and +6us (same counters with/without the
// aw reorder). __expf / fp32-div forms restored (v5-proven clean).
// Ordering lesson (v1/v4/v6/v8): keep v5's load/compute placement exactly.
// No __syncthreads: LDS regions are wave-private; DS pipe is in-order
// within a wave.
//
// rows=200000, RANK=64, WINDOW=11. Block=256 (4 waves), 16 rows/wave/tile.

constexpr int RANK   = 64;
constexpr int WINDOW = 11;
constexpr int PAD    = 5;
constexpr int TILE   = 16;   // rows per wave
constexpr int BLOCK  = 256;  // 4 waves
constexpr int TR     = 64;   // rows per block-tile
constexpr int BROWS  = 28;   // staged band rows (rw-5 .. rw+22)
constexpr int BSTR   = 68;   // band row stride (floats): 272B, 16B-aligned
constexpr int GRIDB  = 1280; // 5 resident blocks/CU x 256 CU (LDS-capped)

constexpr int BAND_F = BROWS * BSTR;            // 1904 floats per wave
// + 4 pad rows: wave 3's dead abnd reads touch band rows 28..31.
constexpr int SMEMF  = 4 * BAND_F + 4 * BSTR;   // 7888 floats = 31552 B

typedef short short8  __attribute__((ext_vector_type(8)));
typedef float float4v __attribute__((ext_vector_type(4)));

__device__ __forceinline__ short8 cvt_bf8(float4 a, float4 b) {
    union { short8 s; __hip_bfloat162 h[4]; } u;
    u.h[0] = __float22bfloat162_rn(make_float2(a.x, a.y));
    u.h[1] = __float22bfloat162_rn(make_float2(a.z, a.w));
    u.h[2] = __float22bfloat162_rn(make_float2(b.x, b.y));
    u.h[3] = __float22bfloat162_rn(make_float2(b.z, b.w));
    return u.s;
}

__device__ __forceinline__ float fast_tanh(float x) {
    return 1.0f - 2.0f / (1.0f + __expf(2.0f * x));
}

__global__ __launch_bounds__(BLOCK)
__attribute__((amdgpu_waves_per_eu(4, 4)))
void attn_win_kernel(
    const float* __restrict__ A,   // (rows, 64)
    const float* __restrict__ W,   // (64, 64) row-major (out,in)
    const float* __restrict__ b,   // (64,)
    float* __restrict__ out,       // (rows, 64)
    int rows)
{
    // Flat LDS so the deliberate band-row over-reads (rows 28..31, dead
    // data) stay in-bounds of the block allocation (4-row tail pad).
    __shared__ __align__(16) float smem[SMEMF];

    const int lane = threadIdx.x & 63;
    const int wv   = threadIdx.x >> 6;
    const int m16  = lane & 15;
    const int quad = lane >> 4;
    const int sr   = lane >> 4;        // staging: row within group-of-4
    const int sc4  = (lane & 15) * 4;  // staging: col base (float4)
    const int dql  = quad * 4 - m16;   // per-lane window-membership base

    float* const bandW = smem + wv * BAND_F;   // [28][68]

    // ---- Persistent W fragments (32 VGPRs) + transposed bias, loaded ONCE ----
    short8 wfrag[4][2];  // [ct][kf]: W[ct*16+m16][kf*32 + quad*8 + j]
    #pragma unroll
    for (int ct = 0; ct < 4; ct++) {
        #pragma unroll
        for (int kf = 0; kf < 2; kf++) {
            const float4* p =
                (const float4*)(W + (ct * 16 + m16) * RANK + kf * 32 + quad * 8);
            wfrag[ct][kf] = cvt_bf8(p[0], p[1]);
        }
    }
    float4 biasT[4];
    #pragma unroll
    for (int ct = 0; ct < 4; ct++)
        biasT[ct] = *(const float4*)(b + ct * 16 + quad * 4);

    // bpermute source-lane indices (byte units): word w of B-frag comes from
    // lane m16 + 16*(2*(quad&1) + (w>>1)).
    const int idxA = 4 * m16 + 128 * (quad & 1);
    const int idxB = idxA + 64;

    const int n_btiles = (rows + TR - 1) / TR;
    int bt = blockIdx.x;
    if (bt >= n_btiles) return;

    // ---- prologue: stage FIRST tile's 28-row fp32 band (guarded) ----
    {
        const int rw0 = bt * TR + wv * TILE;
        #pragma unroll
        for (int ro = 0; ro < 7; ro++) {
            const int g = rw0 - PAD + ro * 4 + sr;
            float4 x = make_float4(0.f, 0.f, 0.f, 0.f);
            if ((unsigned)g < (unsigned)rows)
                x = *(const float4*)(A + (size_t)g * RANK + sc4);
            *(float4*)&bandW[(ro * 4 + sr) * BSTR + sc4] = x;
        }
    }

    for (; bt < n_btiles; bt += gridDim.x) {
        const int rw = bt * TR + wv * TILE;   // this wave's rows rw..rw+15

        // ---- am1 frags from band (fp32 -> bf16): A rows rw+m16 ----
        short8 am1[2];
        #pragma unroll
        for (int kf = 0; kf < 2; kf++) {
            const float4* pp =
                (const float4*)&bandW[(PAD + m16) * BSTR + kf * 32 + quad * 8];
            am1[kf] = cvt_bf8(pp[0], pp[1]);
        }

        // ---- M1 (transposed): accT[ct] = W-block(ct) x A^T + b ----
        // C element: v1[m = m16][n = ct*16 + quad*4 + r]
        float4v accT[4];
        #pragma unroll
        for (int ct = 0; ct < 4; ct++)
            accT[ct] = (float4v){biasT[ct].x, biasT[ct].y,
                                 biasT[ct].z, biasT[ct].w};
        #pragma unroll
        for (int kf = 0; kf < 2; kf++)
            #pragma unroll
            for (int ct = 0; ct < 4; ct++)
                accT[ct] = __builtin_amdgcn_mfma_f32_16x16x32_bf16(
                    wfrag[ct][kf], am1[kf], accT[ct], 0, 0, 0);

        // ---- tanh + pack to bf16 pairs ----
        int pk[4][2];
        #pragma unroll
        for (int ct = 0; ct < 4; ct++)
            #pragma unroll
            for (int u = 0; u < 2; u++) {
                union { __hip_bfloat162 h; int i; } cv;
                cv.h = __float22bfloat162_rn(make_float2(
                    fast_tanh(accT[ct][2 * u]),
                    fast_tanh(accT[ct][2 * u + 1])));
                pk[ct][u] = cv.i;
            }

        // ---- M2 B-frag gather via ds_bpermute (no LDS storage) ----
        short8 bfr[2];
        #pragma unroll
        for (int kf = 0; kf < 2; kf++) {
            union { int w[4]; short8 s; } u;
            #pragma unroll
            for (int w = 0; w < 4; w++) {
                const int idx = (w >> 1) ? idxB : idxA;
                const int lo = __builtin_amdgcn_ds_bpermute(idx, pk[2 * kf][w & 1]);
                const int hi = __builtin_amdgcn_ds_bpermute(idx, pk[2 * kf + 1][w & 1]);
                u.w[w] = (quad >= 2) ? hi : lo;
            }
            bfr[kf] = u.s;
        }

        // ---- abnd frags: band rows it*16+m16 (rows 28..31 are dead reads) ----
        short8 abnd[2][2];
        #pragma unroll
        for (int it = 0; it < 2; it++)
            #pragma unroll
            for (int kf = 0; kf < 2; kf++) {
                const float4* pp = (const float4*)
                    &bandW[(it * 16 + m16) * BSTR + kf * 32 + quad * 8];
                abnd[it][kf] = cvt_bf8(pp[0], pp[1]);
            }

        // ---- issue NEXT tile's stage loads (v5 placement, spill-free) ----
        float4 stg[7];
        {
            const int rwn = rw + (int)gridDim.x * TR;
            #pragma unroll
            for (int ro = 0; ro < 7; ro++) {
                const int g = rwn - PAD + ro * 4 + sr;
                stg[ro] = make_float4(0.f, 0.f, 0.f, 0.f);
                if ((unsigned)g < (unsigned)rows)
                    stg[ro] = *(const float4*)(A + (size_t)g * RANK + sc4);
            }
        }

        // ---- M2: S[i][q] = dot(band[i], v1[q]) ----
        float4v sacc[2];
        sacc[0] = (float4v){0.f, 0.f, 0.f, 0.f};
        sacc[1] = (float4v){0.f, 0.f, 0.f, 0.f};
        #pragma unroll
        for (int kf = 0; kf < 2; kf++)
            #pragma unroll
            for (int it = 0; it < 2; it++)
                sacc[it] = __builtin_amdgcn_mfma_f32_16x16x32_bf16(
                    abnd[it][kf], bfr[kf], sacc[it], 0, 0, 0);

        // ---- softmax IN REGISTERS over band i in [q, q+10], q = m16 ----
        // Lane (m16,quad) holds S[i][m16] for i = it*16+quad*4+rg.
        // Mask out-of-window to -3e38 (exp -> 0); reduce max/sum across
        // the 4 quads sharing column m16 via xor-16/xor-32 butterflies.
        float sm[2][4];
        float mx = -3.0e38f;
        #pragma unroll
        for (int it = 0; it < 2; it++)
            #pragma unroll
            for (int rg = 0; rg < 4; rg++) {
                const int c = it * 16 + rg;
                const bool in = (unsigned)(dql + c) <= 10u;
                const float v = in ? sacc[it][rg] : -3.0e38f;
                sm[it][rg] = v;
                mx = fmaxf(mx, v);
            }
        mx = fmaxf(mx, __shfl_xor(mx, 16));
        mx = fmaxf(mx, __shfl_xor(mx, 32));
        float den = 0.0f;
        #pragma unroll
        for (int it = 0; it < 2; it++)
            #pragma unroll
            for (int rg = 0; rg < 4; rg++) {
                const float e = __expf((sm[it][rg] - mx) * 0.125f);
                sm[it][rg] = e;   // 1/sqrt(64) folded into the scale
                den += e;
            }
        den += __shfl_xor(den, 16);
        den += __shfl_xor(den, 32);
        const float rden = __fdividef(1.0f, den);
        #pragma unroll
        for (int it = 0; it < 2; it++)
            #pragma unroll
            for (int rg = 0; rg < 4; rg++)
                sm[it][rg] *= rden;

        // ---- aw: fp32 window, last reads of the current band (v5 placement) ----
        float aw[26];
        #pragma unroll
        for (int s = 0; s < 26; s++) aw[s] = bandW[s * BSTR + lane];

        // ---- overwrite band with NEXT tile's rows (DS in-order per wave) ----
        #pragma unroll
        for (int ro = 0; ro < 7; ro++)
            *(float4*)&bandW[(ro * 4 + sr) * BSTR + sc4] = stg[ro];

        // ---- P4: out[rw+rr][lane] = sum_w P[rr][w] * aw[rr+w] ----
        // Prob for (col rr, band row i=rr+w) lives in lane ((i&15)>>2)*16+rr,
        // reg sm[i>>4][i&3] — all compile-time after unroll.
        #pragma unroll
        for (int rr = 0; rr < TILE; rr++) {
            float o = 0.0f;
            #pragma unroll
            for (int w = 0; w < WINDOW; w++) {
                const int i  = rr + w;
                const int ln = ((i & 15) >> 2) * 16 + rr;
                const float pw = __uint_as_float(__builtin_amdgcn_readlane(
                    __float_as_uint(sm[i >> 4][i & 3]), ln));
                o = fmaf(pw, aw[rr + w], o);
            }
            if (rw + rr < rows)   // wave-uniform scalar guard
                out[(size_t)(rw + rr) * RANK + lane] = o;
        }
    }
}

extern "C" void kernel_launch(void* const* d_in, const int* in_sizes, int n_in,
                              void* d_out, int out_size, void* d_ws, size_t ws_size,
                              hipStream_t stream) {
    const float* A = (const float*)d_in[0];
    const float* W = (const float*)d_in[1];
    const float* b = (const float*)d_in[2];
    float* out = (float*)d_out;

    const int rows     = in_sizes[0] / RANK;
    const int n_btiles = (rows + TR - 1) / TR;
    const int blocks   = n_btiles < GRIDB ? n_btiles : GRIDB;  // persistent

    hipLaunchKernelGGL(attn_win_kernel, dim3(blocks), dim3(BLOCK), 0, stream,
                       A, W, b, out, rows);
}